// Round 8
// baseline (447.310 us; speedup 1.0000x reference)
//
#include <hip/hip_runtime.h>
#include <math.h>

typedef _Float16 v8h __attribute__((ext_vector_type(8)));
typedef float v4f __attribute__((ext_vector_type(4)));
typedef float v16f __attribute__((ext_vector_type(16)));

// ---------------------------------------------------------------- repack + mlp (LDS users only)
// R7 grid: 264 blocks. rc: 2 co/block, bb: 4 co/block; LDS stage 18.5 KB.
__global__ void __launch_bounds__(256) prep_repack_kernel(
    const float* __restrict__ rc_w, const float* __restrict__ bb_w1,
    const float* __restrict__ bb_w2, const float* __restrict__ dp_w,
    const float* __restrict__ sps,
    const float* __restrict__ fc1_w, const float* __restrict__ fc1_b,
    const float* __restrict__ fc2_w, const float* __restrict__ fc2_b,
    const float* __restrict__ se_rw, const float* __restrict__ se_rb,
    const float* __restrict__ se_ew, const float* __restrict__ se_eb,
    _Float16* __restrict__ wrc, _Float16* __restrict__ wbb,
    _Float16* __restrict__ wdp, float* __restrict__ sig) {
  const int bx = blockIdx.x;
  const int tid = threadIdx.x;
  __shared__ float lds[4612];  // 18,448 B; padded weight stage / mlp buf

  if (bx < 64) {  // ---- rc repack: co-group of 2, src 2x2304 f32 coalesced
    const float* src = rc_w + (size_t)bx * 2 * 2304;
#pragma unroll
    for (int r = 0; r < 18; ++r) {
      int e = r * 256 + tid;            // 0..4607
      int col = e / 2304;               // 0..1
      int rem = e - col * 2304;
      lds[col * 2305 + rem] = src[e];   // +1 pad breaks col-bank aliasing
    }
    __syncthreads();
#pragma unroll
    for (int ro = 0; ro < 3; ++ro) {
      int lidx = ro * 256 + tid;  // 576 slots = 16 c16 x 9 tap x 2 kh x 2 col
      if (lidx < 576) {
        int col = lidx & 1;
        int r = lidx >> 1;        // ((c16*9+tap)*2+kh)
        int kh = r & 1;
        int ct = r >> 1;
        int tap = ct % 9, c16 = ct / 9;
        v8h o;
#pragma unroll
        for (int j = 0; j < 8; ++j)
          o[j] = (_Float16)lds[col * 2305 + (c16 * 16 + kh * 8 + j) * 9 + tap];
        *(v8h*)(wrc + ((size_t)r * 128 + bx * 2 + col) * 8) = o;
      }
    }
  } else if (bx < 256) {  // ---- bb repack: conv k, co-group of 4
    const int t = bx - 64;
    const int k = t >> 5, g = t & 31;
    const float* base = (k < 3) ? (bb_w1 + (size_t)k * 147456)
                                : (bb_w2 + (size_t)(k - 3) * 147456);
    const int cslot = (k < 3) ? (2 * k) : (2 * (k - 3) + 1);
    const float* src = base + (size_t)g * 4 * 1152;
#pragma unroll
    for (int r = 0; r < 18; ++r) {
      int e = r * 256 + tid;            // 0..4607
      int col = e / 1152;               // 0..3
      int rem = e - col * 1152;
      lds[col * 1153 + rem] = src[e];
    }
    __syncthreads();
#pragma unroll
    for (int ro = 0; ro < 3; ++ro) {
      int lidx = ro * 256 + tid;  // 576 slots = 8 c16 x 9 tap x 2 kh x 4 col
      if (lidx < 576) {
        int col = lidx & 3;
        int r = lidx >> 2;        // ((c16*9+tap)*2+kh), c16<8
        int kh = r & 1;
        int ct = r >> 1;
        int tap = ct % 9, c16 = ct / 9;
        v8h o;
#pragma unroll
        for (int j = 0; j < 8; ++j)
          o[j] = (_Float16)lds[col * 1153 + (c16 * 16 + kh * 8 + j) * 9 + tap];
        *(v8h*)(wbb + (size_t)cslot * 147456 + ((size_t)r * 128 + g * 4 + col) * 8) = o;
      }
    }
  } else if (bx < 263) {  // ---- dp: flat, coalesced both sides
    int s3 = (bx - 256) * 256 + tid;  // < 1792
    v8h o;
#pragma unroll
    for (int j = 0; j < 8; ++j) o[j] = (_Float16)dp_w[(size_t)s3 * 8 + j];
    *(v8h*)(wdp + (size_t)s3 * 8) = o;
  } else {  // ---- mlp (first 128 lanes compute; barriers uniform)
    const int j = tid;
    const bool on = j < 128;
    for (int b = 0; b < 4; ++b) {
      float h1 = 0.f;
      if (on) h1 = fmaxf(sps[b] * fc1_w[j] + fc1_b[j], 0.f);
      __syncthreads();
      if (on) lds[j] = h1;
      __syncthreads();
      float hm = 0.f;
      if (on) {
        hm = fc2_b[j];
        for (int k = 0; k < 128; ++k) hm += lds[k] * fc2_w[j * 128 + k];
      }
      __syncthreads();
      if (on) lds[j] = hm;
      __syncthreads();
      float t = 0.f;
      if (on) {
        t = se_rb[j];
        for (int k = 0; k < 128; ++k) t += lds[k] * se_rw[j * 128 + k];
        t = fmaxf(t, 0.f);
      }
      __syncthreads();
      if (on) lds[j] = t;
      __syncthreads();
      if (on) {
        float se = se_eb[j];
        for (int k = 0; k < 128; ++k) se += lds[k] * se_ew[j * 128 + k];
        sig[b * 128 + j] = 1.f / (1.f + expf(-se));
      }
      __syncthreads();
    }
  }
}

// ---------------------------------------------------------------- NCHW f32 -> NHWC f16 convert
// R6: LDS-free, full-lane-utilization, max loads-in-flight. Thread = flat
// position i, blockIdx.y = 64-channel quarter; 64 gathers into registers,
// 128B contiguous v8h stores. Each load = 256B coalesced segment.
__global__ void __launch_bounds__(256) convert_kernel(
    const float* __restrict__ img, _Float16* __restrict__ act16) {
  const int i = blockIdx.x * 256 + threadIdx.x;  // 0..44799
  const int cq = blockIdx.y;                     // 0..3
  const int n = i / 11200;
  const int hw = i - n * 11200;
  const float* ip = img + (size_t)n * 2867200 + (size_t)(cq * 64) * 11200 + hw;
  float v[64];
#pragma unroll
  for (int k = 0; k < 64; ++k) v[k] = ip[(size_t)k * 11200];
  _Float16* op = act16 + (size_t)i * 256 + cq * 64;
#pragma unroll
  for (int g = 0; g < 8; ++g) {
    v8h o;
#pragma unroll
    for (int j = 0; j < 8; ++j) o[j] = (_Float16)v[g * 8 + j];
    *(v8h*)(op + g * 8) = o;
  }
}

// ---------------------------------------------------------------- 3x3 conv, implicit GEMM, 32x32x16 f16 MFMA
// R8: residency re-structure. R1-R7 ledger: MfmaUtil pinned 21-27% across
// occupancy/tile/LDS-traffic/pipeline-depth variations; per-CU arithmetic
// shows (a) 2-blocks/CU x 392 blocks = 24% machine idle from imbalance,
// (b) LDS pipe ~74% busy on the critical 2-block CUs. Both improve with
// more, smaller blocks -- WITHOUT touching the proven wave tile:
//   block = 4h x 32w x 64cout, 4 waves (256 thr), wave = 2h x 32w x 32co.
//   LDS: A dbuf 2x6.4KB (6x34 halo) + B dbuf 2x18.4KB = 49.9 KB -> 3 blk/CU.
//   grid = 7wt x 14ht x 8z = 784 blocks = 3.06/CU -> 97% balance (was 76%),
//   12 waves/CU, 3 independent barrier groups per CU.
// cout stays 64/block so act16 is read only 2x -> FETCH ~28 MB (R3's 4x
// A-re-read mistake avoided). Flat grid + XCD swizzle (fid&7)*98+fid>>3:
// 784 = 8x98 -> each XCD owns one (n,cg) slice; B slice 295KB + act slice
// 5.7MB stay in its private L2.
// MODE 0: out = relu((conv + bias)*s + t) * sig_se          (rc conv)
// MODE 1: out = relu(conv*s + t)                            (bb conv1)
// MODE 2: out = relu(xprev + conv*s + t)                    (bb conv2 + residual)
template <int CIN, int MODE>
__global__ void __launch_bounds__(256, 3) conv3x3_kernel(
    const _Float16* __restrict__ act, const _Float16* __restrict__ wr,
    const _Float16* __restrict__ xprev, const float* __restrict__ bias,
    const float* __restrict__ sc, const float* __restrict__ tr,
    const float* __restrict__ sig_se, _Float16* __restrict__ out) {
  constexpr int NCH = CIN / 16;  // 16 (rc) or 8 (bb)
  const int fid = blockIdx.x;
  const int swz = (fid & 7) * 98 + (fid >> 3);  // XCD-pinned: z = swz/98
  const int zz = swz / 98;
  const int tt = swz - zz * 98;
  const int ht = tt / 7, wt = tt - ht * 7;
  const int n = zz >> 1, cg = zz & 1;
  const int h0 = ht * 4, w0 = wt * 32;
  const int tid = threadIdx.x;
  const int wave = tid >> 6, lane = tid & 63;
  const int l31 = lane & 31, khalf = lane >> 5;
  const int wv = wave >> 1, kc = wave & 1;

  __shared__ alignas(16) _Float16 ldsA[2][2 * 204 * 8];  // 6,528 B per buf
  __shared__ alignas(16) _Float16 ldsB[2][1152 * 8];     // 18,432 B per buf

  // ---- A staging map: 408 v8h slots (2 parts x 204 pos = 6h x 34w) / 2 rounds
  size_t goffA[2];
  int loffA[2];
  bool exA[2], okA[2];
#pragma unroll
  for (int it = 0; it < 2; ++it) {
    int slot = it * 256 + tid;
    int pos = slot >> 1, part = slot & 1;  // 2 lanes = 32B contiguous global
    int hh = pos / 34, ww = pos - hh * 34;
    int gh = h0 - 1 + hh, gw = w0 - 1 + ww;
    exA[it] = slot < 408;
    bool inimg = (unsigned)gh < 56u && (unsigned)gw < 200u;
    okA[it] = exA[it] && inimg;
    loffA[it] = (part * 204 + pos) * 8;
    int ghc = okA[it] ? gh : 0, gwc = okA[it] ? gw : 0;
    goffA[it] = (((size_t)n * 56 + ghc) * 200 + gwc) * CIN + part * 8;
  }
  // ---- B staging map: 1152 v8h slots (9 tap x 2 kh x 64 cout) over 5 rounds
  size_t goffB[5];
  int loffB[5];
  bool exB[5];
#pragma unroll
  for (int it = 0; it < 5; ++it) {
    int slot = it * 256 + tid;
    exB[it] = slot < 1152;
    int s = exB[it] ? slot : 0;
    int tap = s >> 7, kh = (s >> 6) & 1, co = s & 63;
    goffB[it] = (((size_t)(tap * 2 + kh)) * 128 + cg * 64 + co) * 8;  // chunk-0 offset
    loffB[it] = s * 8;
  }

  const v8h zero8 = {(_Float16)0, (_Float16)0, (_Float16)0, (_Float16)0,
                     (_Float16)0, (_Float16)0, (_Float16)0, (_Float16)0};
  v8h preA[2], preB[5];
#pragma unroll
  for (int it = 0; it < 2; ++it) preA[it] = okA[it] ? *(const v8h*)(act + goffA[it]) : zero8;
#pragma unroll
  for (int it = 0; it < 5; ++it) preB[it] = exB[it] ? *(const v8h*)(wr + goffB[it]) : zero8;

  v16f acc[2];
#pragma unroll
  for (int mt = 0; mt < 2; ++mt)
#pragma unroll
    for (int r = 0; r < 16; ++r) acc[mt][r] = 0.f;

#pragma unroll 1
  for (int c = 0; c < NCH; ++c) {
    _Float16* aB = &ldsA[c & 1][0];
    _Float16* bB = &ldsB[c & 1][0];
    // commit prefetched chunk
#pragma unroll
    for (int it = 0; it < 2; ++it)
      if (exA[it]) *(v8h*)(aB + loffA[it]) = preA[it];
#pragma unroll
    for (int it = 0; it < 5; ++it)
      if (exB[it]) *(v8h*)(bB + loffB[it]) = preB[it];
    __syncthreads();
    // prefetch next chunk (hidden behind this chunk's MFMA block)
    if (c + 1 < NCH) {
#pragma unroll
      for (int it = 0; it < 2; ++it)
        preA[it] = okA[it] ? *(const v8h*)(act + goffA[it] + (size_t)(c + 1) * 16) : zero8;
#pragma unroll
      for (int it = 0; it < 5; ++it)
        preB[it] = exB[it] ? *(const v8h*)(wr + goffB[it] + (size_t)(c + 1) * 18432) : zero8;
    }
    // compute: dx outer, 4 A-rows reused across dy (6 MFMAs per 4 A-reads)
#pragma unroll
    for (int dx = 0; dx < 3; ++dx) {
      v8h a[4];
#pragma unroll
      for (int r = 0; r < 4; ++r)
        a[r] = *(const v8h*)(aB + (khalf * 204 + (wv * 2 + r) * 34 + l31 + dx) * 8);
#pragma unroll
      for (int dy = 0; dy < 3; ++dy) {
        v8h bf = *(const v8h*)(bB + ((dy * 3 + dx) * 128 + khalf * 64 + kc * 32 + l31) * 8);
        acc[0] = __builtin_amdgcn_mfma_f32_32x32x16_f16(a[dy], bf, acc[0], 0, 0, 0);
        acc[1] = __builtin_amdgcn_mfma_f32_32x32x16_f16(a[dy + 1], bf, acc[1], 0, 0, 0);
      }
    }
    __syncthreads();
  }

  // epilogue: D layout col(N=cout)=l31, row(M=w-offset)=(r&3)+8*(r>>2)+4*khalf
#pragma unroll
  for (int mt = 0; mt < 2; ++mt) {
    const int h = h0 + wv * 2 + mt;
    const int cc = cg * 64 + kc * 32 + l31;
    const float s = sc[cc], t = tr[cc];
    float bb = 0.f, sg = 1.f;
    if constexpr (MODE == 0) {
      bb = bias[cc];
      sg = sig_se[n * 128 + cc];
    }
#pragma unroll
    for (int r = 0; r < 16; ++r) {
      const int m = (r & 3) + 8 * (r >> 2) + 4 * khalf;
      const int w = w0 + m;
      if (w < 200) {
        float v = acc[mt][r];
        size_t oidx = (((size_t)n * 56 + h) * 200 + w) * 128 + cc;
        if constexpr (MODE == 0) v = fmaxf((v + bb) * s + t, 0.f) * sg;
        if constexpr (MODE == 1) v = fmaxf(v * s + t, 0.f);
        if constexpr (MODE == 2) v = fmaxf((float)xprev[oidx] + v * s + t, 0.f);
        out[oidx] = (_Float16)v;
      }
    }
  }
}

// ---------------------------------------------------------------- depth proj (MFMA) + fused softmax
// x: [44800][128] f16; wdp: [112][128] f16; dp_b: [112] f32
// depth out: f16 [pos][112] (z-contiguous for gridsample)
__global__ void __launch_bounds__(256) depth_proj_softmax_kernel(
    const _Float16* __restrict__ x, const _Float16* __restrict__ wdp,
    const float* __restrict__ dp_b, _Float16* __restrict__ depth) {
  const int wave = threadIdx.x >> 6, lane = threadIdx.x & 63;
  const int q = lane >> 4, l16 = lane & 15;
  const int pos0 = blockIdx.x * 64 + wave * 16;

  v4f acc[7];
#pragma unroll
  for (int nt = 0; nt < 7; ++nt) {
    float bv = dp_b[nt * 16 + l16];
    acc[nt] = {bv, bv, bv, bv};
  }
#pragma unroll
  for (int c0 = 0; c0 < 128; c0 += 32) {
    v8h a = *(const v8h*)(x + (size_t)(pos0 + l16) * 128 + c0 + q * 8);
#pragma unroll
    for (int nt = 0; nt < 7; ++nt) {
      v8h b = *(const v8h*)(wdp + (size_t)(nt * 16 + l16) * 128 + c0 + q * 8);
      acc[nt] = __builtin_amdgcn_mfma_f32_16x16x32_f16(a, b, acc[nt], 0, 0, 0);
    }
  }
  float m[4];
#pragma unroll
  for (int r = 0; r < 4; ++r) {
    m[r] = acc[0][r];
#pragma unroll
    for (int nt = 1; nt < 7; ++nt) m[r] = fmaxf(m[r], acc[nt][r]);
  }
#pragma unroll
  for (int off = 1; off < 16; off <<= 1)
#pragma unroll
    for (int r = 0; r < 4; ++r) m[r] = fmaxf(m[r], __shfl_xor(m[r], off));
  float s[4] = {0.f, 0.f, 0.f, 0.f};
#pragma unroll
  for (int nt = 0; nt < 7; ++nt)
#pragma unroll
    for (int r = 0; r < 4; ++r) {
      float e = expf(acc[nt][r] - m[r]);
      acc[nt][r] = e;
      s[r] += e;
    }
#pragma unroll
  for (int off = 1; off < 16; off <<= 1)
#pragma unroll
    for (int r = 0; r < 4; ++r) s[r] += __shfl_xor(s[r], off);
#pragma unroll
  for (int r = 0; r < 4; ++r) {
    const float inv = 1.f / s[r];
    const size_t p = pos0 + q * 4 + r;
#pragma unroll
    for (int nt = 0; nt < 7; ++nt)
      depth[p * 112 + nt * 16 + l16] = (_Float16)(acc[nt][r] * inv);
  }
}

// ---------------------------------------------------------------- trilinear grid sample (C=1)
__global__ void __launch_bounds__(256) gridsample_kernel(
    const float* __restrict__ grids, const _Float16* __restrict__ depth,
    float* __restrict__ out) {
  const int i = blockIdx.x * 256 + threadIdx.x;
  const int n = i >> 18;
  const float gx = grids[(size_t)i * 3];
  const float gy = grids[(size_t)i * 3 + 1];
  const float gz = grids[(size_t)i * 3 + 2];
  const float ix = (gx + 1.f) * 100.f - 0.5f;
  const float iy = (gy + 1.f) * 28.f - 0.5f;
  const float iz = (gz + 1.f) * 56.f - 0.5f;
  const float xf = floorf(ix), yf = floorf(iy), zf = floorf(iz);
  const int x0 = (int)xf, y0 = (int)yf, z0 = (int)zf;
  const float fx = ix - xf, fy = iy - yf, fz = iz - zf;
  const bool zv0 = (unsigned)z0 < 112u;
  const bool zv1 = (unsigned)(z0 + 1) < 112u;
  const float wz0 = 1.f - fz, wz1 = fz;
  float acc = 0.f;
#pragma unroll
  for (int dy = 0; dy < 2; ++dy) {
    const int yi = y0 + dy;
    const float wy = dy ? fy : 1.f - fy;
#pragma unroll
    for (int dx = 0; dx < 2; ++dx) {
      const int xi = x0 + dx;
      const float wx = dx ? fx : 1.f - fx;
      if ((unsigned)xi < 200u && (unsigned)yi < 56u) {
        const _Float16* bp = depth + ((size_t)n * 11200 + yi * 200 + xi) * 112;
        float v0 = zv0 ? (float)bp[z0] : 0.f;
        float v1 = zv1 ? (float)bp[z0 + 1] : 0.f;
        acc += (wx * wy) * (wz0 * v0 + wz1 * v1);
      }
    }
  }
  out[i] = acc;
}

// ---------------------------------------------------------------- launch
extern "C" void kernel_launch(void* const* d_in, const int* in_sizes, int n_in,
                              void* d_out, int out_size, void* d_ws, size_t ws_size,
                              hipStream_t stream) {
  (void)in_sizes; (void)n_in; (void)out_size; (void)ws_size;
  const float* img = (const float*)d_in[0];
  const float* sps = (const float*)d_in[1];
  const float* grids = (const float*)d_in[2];
  const float* rc_w = (const float*)d_in[3];
  const float* rc_b = (const float*)d_in[4];
  const float* rc_s = (const float*)d_in[5];
  const float* rc_t = (const float*)d_in[6];
  const float* fc1_w = (const float*)d_in[7];
  const float* fc1_b = (const float*)d_in[8];
  const float* fc2_w = (const float*)d_in[9];
  const float* fc2_b = (const float*)d_in[10];
  const float* se_rw = (const float*)d_in[11];
  const float* se_rb = (const float*)d_in[12];
  const float* se_ew = (const float*)d_in[13];
  const float* se_eb = (const float*)d_in[14];
  const float* bb_w1 = (const float*)d_in[15];
  const float* bb_s1 = (const float*)d_in[16];
  const float* bb_t1 = (const float*)d_in[17];
  const float* bb_w2 = (const float*)d_in[18];
  const float* bb_s2 = (const float*)d_in[19];
  const float* bb_t2 = (const float*)d_in[20];
  const float* dp_w = (const float*)d_in[21];
  const float* dp_b = (const float*)d_in[22];
  float* outp = (float*)d_out;

  char* ws = (char*)d_ws;
  _Float16* act16 = (_Float16*)(ws + 0);
  _Float16* depth16 = (_Float16*)(ws + 0);  // reuses act16 slot (act16 dead post rc-conv)
  _Float16* xa = (_Float16*)(ws + 23068672);
  _Float16* xb = (_Float16*)(ws + 23068672 + 11534336);
  _Float16* yb = (_Float16*)(ws + 23068672 + 2 * 11534336);
  _Float16* wrc = (_Float16*)(ws + 57671680);           // 589,824 B
  _Float16* wdp = (_Float16*)(ws + 57671680 + 589824);  // 28,672 B
  _Float16* wbb = (_Float16*)(ws + 58327040);           // 1,769,472 B
  float* sig = (float*)(ws + 58327040 + 1769472);       // 2,048 B

  prep_repack_kernel<<<dim3(264), 256, 0, stream>>>(
      rc_w, bb_w1, bb_w2, dp_w, sps, fc1_w, fc1_b, fc2_w, fc2_b, se_rw, se_rb,
      se_ew, se_eb, wrc, wbb, wdp, sig);
  convert_kernel<<<dim3(175, 4), 256, 0, stream>>>(img, act16);

  dim3 cgrid(784);  // 4h x 32w x 64cout, 784 blocks x 4 waves, 3 blk/CU
  conv3x3_kernel<256, 0><<<cgrid, 256, 0, stream>>>(act16, wrc, nullptr, rc_b, rc_s,
                                                    rc_t, sig, xa);
  _Float16* xcur = xa;
  _Float16* xnxt = xb;
  for (int i = 0; i < 3; ++i) {
    conv3x3_kernel<128, 1><<<cgrid, 256, 0, stream>>>(
        xcur, wbb + (size_t)(2 * i) * 147456, nullptr, nullptr, bb_s1 + i * 128,
        bb_t1 + i * 128, nullptr, yb);
    conv3x3_kernel<128, 2><<<cgrid, 256, 0, stream>>>(
        yb, wbb + (size_t)(2 * i + 1) * 147456, xcur, nullptr, bb_s2 + i * 128,
        bb_t2 + i * 128, nullptr, xnxt);
    _Float16* t = xcur;
    xcur = xnxt;
    xnxt = t;
  }

  depth_proj_softmax_kernel<<<dim3(700), 256, 0, stream>>>(xcur, wdp, dp_b, depth16);
  gridsample_kernel<<<dim3(4096), 256, 0, stream>>>(grids, depth16, outp);
}

// Round 9
// 410.357 us; speedup vs baseline: 1.0901x; 1.0901x over previous
//
#include <hip/hip_runtime.h>
#include <math.h>

typedef _Float16 v8h __attribute__((ext_vector_type(8)));
typedef float v4f __attribute__((ext_vector_type(4)));
typedef float v16f __attribute__((ext_vector_type(16)));

// ---------------------------------------------------------------- prep (repack + mlp + convert, ONE launch)
// R9: re-merged. Evidence: R5 (merged, 10 launches) = 407 total; R6/R7 (split,
// 11 launches, SAME conv times) = 421/417 -> the extra launch + cold-L2
// convert cost ~12 us. R5's defect was its 36.9 KB LDS capping ALL blocks at
// 4 blk/CU; this version uses the compact 18.5 KB repack (8 blk/CU) and the
// R6 full-lane register-based convert (zero LDS touched by those blocks).
// blocks [0,64):    rc repack, 2 co per block (LDS transpose, coalesced)
// blocks [64,256):  bb repack, conv k=(bx-64)/32, co-group g=(bx-64)%32 (4 co)
// blocks [256,263): dp copy (flat, coalesced)
// block  263:       tiny MLP + SE sigmoid
// blocks [264,964): NCHW f32 -> NHWC f16 convert; bid=(bx-264): pos-block
//                   bid>>2 (256 positions), channel quarter bid&3; 64 gathers
//                   in flight per thread, 128B contiguous v8h stores.
__global__ void __launch_bounds__(256) prep_kernel(
    const float* __restrict__ rc_w, const float* __restrict__ bb_w1,
    const float* __restrict__ bb_w2, const float* __restrict__ dp_w,
    const float* __restrict__ img, const float* __restrict__ sps,
    const float* __restrict__ fc1_w, const float* __restrict__ fc1_b,
    const float* __restrict__ fc2_w, const float* __restrict__ fc2_b,
    const float* __restrict__ se_rw, const float* __restrict__ se_rb,
    const float* __restrict__ se_ew, const float* __restrict__ se_eb,
    _Float16* __restrict__ wrc, _Float16* __restrict__ wbb,
    _Float16* __restrict__ wdp, _Float16* __restrict__ act16,
    float* __restrict__ sig) {
  const int bx = blockIdx.x;
  const int tid = threadIdx.x;
  __shared__ float lds[4612];  // 18,448 B; padded weight stage / mlp buf

  if (bx < 64) {  // ---- rc repack: co-group of 2, src 2x2304 f32 coalesced
    const float* src = rc_w + (size_t)bx * 2 * 2304;
#pragma unroll
    for (int r = 0; r < 18; ++r) {
      int e = r * 256 + tid;            // 0..4607
      int col = e / 2304;               // 0..1
      int rem = e - col * 2304;
      lds[col * 2305 + rem] = src[e];   // +1 pad breaks col-bank aliasing
    }
    __syncthreads();
#pragma unroll
    for (int ro = 0; ro < 3; ++ro) {
      int lidx = ro * 256 + tid;  // 576 slots = 16 c16 x 9 tap x 2 kh x 2 col
      if (lidx < 576) {
        int col = lidx & 1;
        int r = lidx >> 1;        // ((c16*9+tap)*2+kh)
        int kh = r & 1;
        int ct = r >> 1;
        int tap = ct % 9, c16 = ct / 9;
        v8h o;
#pragma unroll
        for (int j = 0; j < 8; ++j)
          o[j] = (_Float16)lds[col * 2305 + (c16 * 16 + kh * 8 + j) * 9 + tap];
        *(v8h*)(wrc + ((size_t)r * 128 + bx * 2 + col) * 8) = o;
      }
    }
  } else if (bx < 256) {  // ---- bb repack: conv k, co-group of 4
    const int t = bx - 64;
    const int k = t >> 5, g = t & 31;
    const float* base = (k < 3) ? (bb_w1 + (size_t)k * 147456)
                                : (bb_w2 + (size_t)(k - 3) * 147456);
    const int cslot = (k < 3) ? (2 * k) : (2 * (k - 3) + 1);
    const float* src = base + (size_t)g * 4 * 1152;
#pragma unroll
    for (int r = 0; r < 18; ++r) {
      int e = r * 256 + tid;            // 0..4607
      int col = e / 1152;               // 0..3
      int rem = e - col * 1152;
      lds[col * 1153 + rem] = src[e];
    }
    __syncthreads();
#pragma unroll
    for (int ro = 0; ro < 3; ++ro) {
      int lidx = ro * 256 + tid;  // 576 slots = 8 c16 x 9 tap x 2 kh x 4 col
      if (lidx < 576) {
        int col = lidx & 3;
        int r = lidx >> 2;        // ((c16*9+tap)*2+kh), c16<8
        int kh = r & 1;
        int ct = r >> 1;
        int tap = ct % 9, c16 = ct / 9;
        v8h o;
#pragma unroll
        for (int j = 0; j < 8; ++j)
          o[j] = (_Float16)lds[col * 1153 + (c16 * 16 + kh * 8 + j) * 9 + tap];
        *(v8h*)(wbb + (size_t)cslot * 147456 + ((size_t)r * 128 + g * 4 + col) * 8) = o;
      }
    }
  } else if (bx < 263) {  // ---- dp: flat, coalesced both sides
    int s3 = (bx - 256) * 256 + tid;  // < 1792
    v8h o;
#pragma unroll
    for (int j = 0; j < 8; ++j) o[j] = (_Float16)dp_w[(size_t)s3 * 8 + j];
    *(v8h*)(wdp + (size_t)s3 * 8) = o;
  } else if (bx == 263) {  // ---- mlp (first 128 lanes compute; barriers uniform)
    const int j = tid;
    const bool on = j < 128;
    for (int b = 0; b < 4; ++b) {
      float h1 = 0.f;
      if (on) h1 = fmaxf(sps[b] * fc1_w[j] + fc1_b[j], 0.f);
      __syncthreads();
      if (on) lds[j] = h1;
      __syncthreads();
      float hm = 0.f;
      if (on) {
        hm = fc2_b[j];
        for (int k = 0; k < 128; ++k) hm += lds[k] * fc2_w[j * 128 + k];
      }
      __syncthreads();
      if (on) lds[j] = hm;
      __syncthreads();
      float t = 0.f;
      if (on) {
        t = se_rb[j];
        for (int k = 0; k < 128; ++k) t += lds[k] * se_rw[j * 128 + k];
        t = fmaxf(t, 0.f);
      }
      __syncthreads();
      if (on) lds[j] = t;
      __syncthreads();
      if (on) {
        float se = se_eb[j];
        for (int k = 0; k < 128; ++k) se += lds[k] * se_ew[j * 128 + k];
        sig[b * 128 + j] = 1.f / (1.f + expf(-se));
      }
      __syncthreads();
    }
  } else {  // ---- convert: 700 blocks, no LDS use
    const int bid = bx - 264;                      // 0..699
    const int i = (bid >> 2) * 256 + tid;          // 0..44799
    const int cq = bid & 3;                        // 0..3
    const int n = i / 11200;
    const int hw = i - n * 11200;
    const float* ip = img + (size_t)n * 2867200 + (size_t)(cq * 64) * 11200 + hw;
    float v[64];
#pragma unroll
    for (int k = 0; k < 64; ++k) v[k] = ip[(size_t)k * 11200];
    _Float16* op = act16 + (size_t)i * 256 + cq * 64;
#pragma unroll
    for (int g = 0; g < 8; ++g) {
      v8h o;
#pragma unroll
      for (int j = 0; j < 8; ++j) o[j] = (_Float16)v[g * 8 + j];
      *(v8h*)(op + g * 8) = o;
    }
  }
}

// ---------------------------------------------------------------- 3x3 conv, implicit GEMM, 32x32x16 f16 MFMA
// R9: exact revert to R7's conv (best measured: 42.6-42.9 us rc). Conv-
// structure iteration CLOSED: 8 variants (waves/block, tile, LDS traffic
// 27->21 reads/chunk, pipeline depth, block size, balance, XCD swizzle) all
// land 43-54 us, MfmaUtil 21-27%, no saturated pipe -- balanced mix of MFMA
// (~11 us floor) + LDS + staging latency; knobs trade one for another.
// Tile: 8h x 32w x 64cout, grid 7x7x8 = 392 blocks, 512 thr / 8 waves,
// wave tile 2h x 32w x 32cout. 2-deep named prefetch stages; dx-outer
// dy-reuse compute (4 A-reads serve 6 MFMAs). LDS 58.6 KB -> 2 blocks/CU.
// MODE 0: out = relu((conv + bias)*s + t) * sig_se          (rc conv)
// MODE 1: out = relu(conv*s + t)                            (bb conv1)
// MODE 2: out = relu(xprev + conv*s + t)                    (bb conv2 + residual)
template <int CIN, int MODE>
__global__ void __launch_bounds__(512, 4) conv3x3_kernel(
    const _Float16* __restrict__ act, const _Float16* __restrict__ wr,
    const _Float16* __restrict__ xprev, const float* __restrict__ bias,
    const float* __restrict__ sc, const float* __restrict__ tr,
    const float* __restrict__ sig_se, _Float16* __restrict__ out) {
  constexpr int NCH = CIN / 16;  // 16 (rc) or 8 (bb); always even
  const int wt = blockIdx.x, ht = blockIdx.y;
  const int n = blockIdx.z >> 1, cg = blockIdx.z & 1;
  const int h0 = ht * 8, w0 = wt * 32;
  const int tid = threadIdx.x;
  const int wave = tid >> 6, lane = tid & 63;
  const int l31 = lane & 31, khalf = lane >> 5;
  const int wv = wave >> 1, kc = wave & 1;

  __shared__ alignas(16) _Float16 ldsA[2][2 * 340 * 8];  // 10,880 B per buf
  __shared__ alignas(16) _Float16 ldsB[2][1152 * 8];     // 18,432 B per buf

  // ---- A staging map: 680 v8h slots (2 parts x 340 pos) over 2 rounds
  size_t goffA[2];
  int loffA[2];
  bool exA[2], okA[2];
#pragma unroll
  for (int it = 0; it < 2; ++it) {
    int slot = it * 512 + tid;
    int pos = slot >> 1, part = slot & 1;  // 2 lanes = 32B contiguous global
    int hh = pos / 34, ww = pos - hh * 34;
    int gh = h0 - 1 + hh, gw = w0 - 1 + ww;
    exA[it] = slot < 680;
    bool inimg = (unsigned)gh < 56u && (unsigned)gw < 200u;
    okA[it] = exA[it] && inimg;
    loffA[it] = (part * 340 + pos) * 8;
    int ghc = okA[it] ? gh : 0, gwc = okA[it] ? gw : 0;
    goffA[it] = (((size_t)n * 56 + ghc) * 200 + gwc) * CIN + part * 8;
  }
  // ---- B staging map: 1152 v8h slots (9 tap x 2 kh x 64 cout) over 3 rounds
  size_t goffB[3];
  int loffB[3];
  bool exB[3];
#pragma unroll
  for (int it = 0; it < 3; ++it) {
    int slot = it * 512 + tid;
    exB[it] = slot < 1152;
    int s = exB[it] ? slot : 0;
    int tap = s >> 7, kh = (s >> 6) & 1, co = s & 63;
    goffB[it] = (((size_t)(tap * 2 + kh)) * 128 + cg * 64 + co) * 8;  // chunk-0 offset
    loffB[it] = s * 8;
  }

  const v8h zero8 = {(_Float16)0, (_Float16)0, (_Float16)0, (_Float16)0,
                     (_Float16)0, (_Float16)0, (_Float16)0, (_Float16)0};
  // ---- two named prefetch stages (even chunks -> 0, odd chunks -> 1)
  v8h preA0[2], preB0[3], preA1[2], preB1[3];
#pragma unroll
  for (int it = 0; it < 2; ++it) {
    preA0[it] = okA[it] ? *(const v8h*)(act + goffA[it]) : zero8;
    preA1[it] = okA[it] ? *(const v8h*)(act + goffA[it] + 16) : zero8;
  }
#pragma unroll
  for (int it = 0; it < 3; ++it) {
    preB0[it] = exB[it] ? *(const v8h*)(wr + goffB[it]) : zero8;
    preB1[it] = exB[it] ? *(const v8h*)(wr + goffB[it] + 18432) : zero8;
  }

  v16f acc[2];
#pragma unroll
  for (int mt = 0; mt < 2; ++mt)
#pragma unroll
    for (int r = 0; r < 16; ++r) acc[mt][r] = 0.f;

  // per-chunk compute: dx outer, 4 A-rows reused across dy (6 MFMAs / 4 reads)
  auto compute = [&](const _Float16* aB, const _Float16* bB) {
#pragma unroll
    for (int dx = 0; dx < 3; ++dx) {
      v8h a[4];
#pragma unroll
      for (int r = 0; r < 4; ++r)
        a[r] = *(const v8h*)(aB + (khalf * 340 + (wv * 2 + r) * 34 + l31 + dx) * 8);
#pragma unroll
      for (int dy = 0; dy < 3; ++dy) {
        v8h bf = *(const v8h*)(bB + ((dy * 3 + dx) * 128 + khalf * 64 + kc * 32 + l31) * 8);
        acc[0] = __builtin_amdgcn_mfma_f32_32x32x16_f16(a[dy], bf, acc[0], 0, 0, 0);
        acc[1] = __builtin_amdgcn_mfma_f32_32x32x16_f16(a[dy + 1], bf, acc[1], 0, 0, 0);
      }
    }
  };

#pragma unroll 1
  for (int c = 0; c < NCH; c += 2) {
    // ---- even chunk c: commit stage 0, refill for c+2, compute buf 0
#pragma unroll
    for (int it = 0; it < 2; ++it)
      if (exA[it]) *(v8h*)(&ldsA[0][0] + loffA[it]) = preA0[it];
#pragma unroll
    for (int it = 0; it < 3; ++it)
      if (exB[it]) *(v8h*)(&ldsB[0][0] + loffB[it]) = preB0[it];
    if (c + 2 < NCH) {
#pragma unroll
      for (int it = 0; it < 2; ++it)
        preA0[it] = okA[it] ? *(const v8h*)(act + goffA[it] + (size_t)(c + 2) * 16) : zero8;
#pragma unroll
      for (int it = 0; it < 3; ++it)
        preB0[it] = exB[it] ? *(const v8h*)(wr + goffB[it] + (size_t)(c + 2) * 18432) : zero8;
    }
    __syncthreads();
    compute(&ldsA[0][0], &ldsB[0][0]);

    // ---- odd chunk c+1: commit stage 1, refill for c+3, compute buf 1
#pragma unroll
    for (int it = 0; it < 2; ++it)
      if (exA[it]) *(v8h*)(&ldsA[1][0] + loffA[it]) = preA1[it];
#pragma unroll
    for (int it = 0; it < 3; ++it)
      if (exB[it]) *(v8h*)(&ldsB[1][0] + loffB[it]) = preB1[it];
    if (c + 3 < NCH) {
#pragma unroll
      for (int it = 0; it < 2; ++it)
        preA1[it] = okA[it] ? *(const v8h*)(act + goffA[it] + (size_t)(c + 3) * 16) : zero8;
#pragma unroll
      for (int it = 0; it < 3; ++it)
        preB1[it] = exB[it] ? *(const v8h*)(wr + goffB[it] + (size_t)(c + 3) * 18432) : zero8;
    }
    __syncthreads();
    compute(&ldsA[1][0], &ldsB[1][0]);
  }

  // epilogue: D layout col(N=cout)=l31, row(M=w-offset)=(r&3)+8*(r>>2)+4*khalf
#pragma unroll
  for (int mt = 0; mt < 2; ++mt) {
    const int h = h0 + wv * 2 + mt;
    const int cc = cg * 64 + kc * 32 + l31;
    const float s = sc[cc], t = tr[cc];
    float bb = 0.f, sg = 1.f;
    if constexpr (MODE == 0) {
      bb = bias[cc];
      sg = sig_se[n * 128 + cc];
    }
#pragma unroll
    for (int r = 0; r < 16; ++r) {
      const int m = (r & 3) + 8 * (r >> 2) + 4 * khalf;
      const int w = w0 + m;
      if (w < 200) {
        float v = acc[mt][r];
        size_t oidx = (((size_t)n * 56 + h) * 200 + w) * 128 + cc;
        if constexpr (MODE == 0) v = fmaxf((v + bb) * s + t, 0.f) * sg;
        if constexpr (MODE == 1) v = fmaxf(v * s + t, 0.f);
        if constexpr (MODE == 2) v = fmaxf((float)xprev[oidx] + v * s + t, 0.f);
        out[oidx] = (_Float16)v;
      }
    }
  }
}

// ---------------------------------------------------------------- depth proj (MFMA) + fused softmax
// x: [44800][128] f16; wdp: [112][128] f16; dp_b: [112] f32
// depth out: f16 [pos][112] (z-contiguous for gridsample)
__global__ void __launch_bounds__(256) depth_proj_softmax_kernel(
    const _Float16* __restrict__ x, const _Float16* __restrict__ wdp,
    const float* __restrict__ dp_b, _Float16* __restrict__ depth) {
  const int wave = threadIdx.x >> 6, lane = threadIdx.x & 63;
  const int q = lane >> 4, l16 = lane & 15;
  const int pos0 = blockIdx.x * 64 + wave * 16;

  v4f acc[7];
#pragma unroll
  for (int nt = 0; nt < 7; ++nt) {
    float bv = dp_b[nt * 16 + l16];
    acc[nt] = {bv, bv, bv, bv};
  }
#pragma unroll
  for (int c0 = 0; c0 < 128; c0 += 32) {
    v8h a = *(const v8h*)(x + (size_t)(pos0 + l16) * 128 + c0 + q * 8);
#pragma unroll
    for (int nt = 0; nt < 7; ++nt) {
      v8h b = *(const v8h*)(wdp + (size_t)(nt * 16 + l16) * 128 + c0 + q * 8);
      acc[nt] = __builtin_amdgcn_mfma_f32_16x16x32_f16(a, b, acc[nt], 0, 0, 0);
    }
  }
  float m[4];
#pragma unroll
  for (int r = 0; r < 4; ++r) {
    m[r] = acc[0][r];
#pragma unroll
    for (int nt = 1; nt < 7; ++nt) m[r] = fmaxf(m[r], acc[nt][r]);
  }
#pragma unroll
  for (int off = 1; off < 16; off <<= 1)
#pragma unroll
    for (int r = 0; r < 4; ++r) m[r] = fmaxf(m[r], __shfl_xor(m[r], off));
  float s[4] = {0.f, 0.f, 0.f, 0.f};
#pragma unroll
  for (int nt = 0; nt < 7; ++nt)
#pragma unroll
    for (int r = 0; r < 4; ++r) {
      float e = expf(acc[nt][r] - m[r]);
      acc[nt][r] = e;
      s[r] += e;
    }
#pragma unroll
  for (int off = 1; off < 16; off <<= 1)
#pragma unroll
    for (int r = 0; r < 4; ++r) s[r] += __shfl_xor(s[r], off);
#pragma unroll
  for (int r = 0; r < 4; ++r) {
    const float inv = 1.f / s[r];
    const size_t p = pos0 + q * 4 + r;
#pragma unroll
    for (int nt = 0; nt < 7; ++nt)
      depth[p * 112 + nt * 16 + l16] = (_Float16)(acc[nt][r] * inv);
  }
}

// ---------------------------------------------------------------- trilinear grid sample (C=1)
__global__ void __launch_bounds__(256) gridsample_kernel(
    const float* __restrict__ grids, const _Float16* __restrict__ depth,
    float* __restrict__ out) {
  const int i = blockIdx.x * 256 + threadIdx.x;
  const int n = i >> 18;
  const float gx = grids[(size_t)i * 3];
  const float gy = grids[(size_t)i * 3 + 1];
  const float gz = grids[(size_t)i * 3 + 2];
  const float ix = (gx + 1.f) * 100.f - 0.5f;
  const float iy = (gy + 1.f) * 28.f - 0.5f;
  const float iz = (gz + 1.f) * 56.f - 0.5f;
  const float xf = floorf(ix), yf = floorf(iy), zf = floorf(iz);
  const int x0 = (int)xf, y0 = (int)yf, z0 = (int)zf;
  const float fx = ix - xf, fy = iy - yf, fz = iz - zf;
  const bool zv0 = (unsigned)z0 < 112u;
  const bool zv1 = (unsigned)(z0 + 1) < 112u;
  const float wz0 = 1.f - fz, wz1 = fz;
  float acc = 0.f;
#pragma unroll
  for (int dy = 0; dy < 2; ++dy) {
    const int yi = y0 + dy;
    const float wy = dy ? fy : 1.f - fy;
#pragma unroll
    for (int dx = 0; dx < 2; ++dx) {
      const int xi = x0 + dx;
      const float wx = dx ? fx : 1.f - fx;
      if ((unsigned)xi < 200u && (unsigned)yi < 56u) {
        const _Float16* bp = depth + ((size_t)n * 11200 + yi * 200 + xi) * 112;
        float v0 = zv0 ? (float)bp[z0] : 0.f;
        float v1 = zv1 ? (float)bp[z0 + 1] : 0.f;
        acc += (wx * wy) * (wz0 * v0 + wz1 * v1);
      }
    }
  }
  out[i] = acc;
}

// ---------------------------------------------------------------- launch
extern "C" void kernel_launch(void* const* d_in, const int* in_sizes, int n_in,
                              void* d_out, int out_size, void* d_ws, size_t ws_size,
                              hipStream_t stream) {
  (void)in_sizes; (void)n_in; (void)out_size; (void)ws_size;
  const float* img = (const float*)d_in[0];
  const float* sps = (const float*)d_in[1];
  const float* grids = (const float*)d_in[2];
  const float* rc_w = (const float*)d_in[3];
  const float* rc_b = (const float*)d_in[4];
  const float* rc_s = (const float*)d_in[5];
  const float* rc_t = (const float*)d_in[6];
  const float* fc1_w = (const float*)d_in[7];
  const float* fc1_b = (const float*)d_in[8];
  const float* fc2_w = (const float*)d_in[9];
  const float* fc2_b = (const float*)d_in[10];
  const float* se_rw = (const float*)d_in[11];
  const float* se_rb = (const float*)d_in[12];
  const float* se_ew = (const float*)d_in[13];
  const float* se_eb = (const float*)d_in[14];
  const float* bb_w1 = (const float*)d_in[15];
  const float* bb_s1 = (const float*)d_in[16];
  const float* bb_t1 = (const float*)d_in[17];
  const float* bb_w2 = (const float*)d_in[18];
  const float* bb_s2 = (const float*)d_in[19];
  const float* bb_t2 = (const float*)d_in[20];
  const float* dp_w = (const float*)d_in[21];
  const float* dp_b = (const float*)d_in[22];
  float* outp = (float*)d_out;

  char* ws = (char*)d_ws;
  _Float16* act16 = (_Float16*)(ws + 0);
  _Float16* depth16 = (_Float16*)(ws + 0);  // reuses act16 slot (act16 dead post rc-conv)
  _Float16* xa = (_Float16*)(ws + 23068672);
  _Float16* xb = (_Float16*)(ws + 23068672 + 11534336);
  _Float16* yb = (_Float16*)(ws + 23068672 + 2 * 11534336);
  _Float16* wrc = (_Float16*)(ws + 57671680);           // 589,824 B
  _Float16* wdp = (_Float16*)(ws + 57671680 + 589824);  // 28,672 B
  _Float16* wbb = (_Float16*)(ws + 58327040);           // 1,769,472 B
  float* sig = (float*)(ws + 58327040 + 1769472);       // 2,048 B

  prep_kernel<<<dim3(964), 256, 0, stream>>>(
      rc_w, bb_w1, bb_w2, dp_w, img, sps, fc1_w, fc1_b, fc2_w, fc2_b, se_rw, se_rb,
      se_ew, se_eb, wrc, wbb, wdp, act16, sig);

  dim3 cgrid(7, 7, 8);  // 8h x 32w x 64cout, z = n*2 + cg, 392 blocks x 8 waves
  conv3x3_kernel<256, 0><<<cgrid, 512, 0, stream>>>(act16, wrc, nullptr, rc_b, rc_s,
                                                    rc_t, sig, xa);
  _Float16* xcur = xa;
  _Float16* xnxt = xb;
  for (int i = 0; i < 3; ++i) {
    conv3x3_kernel<128, 1><<<cgrid, 512, 0, stream>>>(
        xcur, wbb + (size_t)(2 * i) * 147456, nullptr, nullptr, bb_s1 + i * 128,
        bb_t1 + i * 128, nullptr, yb);
    conv3x3_kernel<128, 2><<<cgrid, 512, 0, stream>>>(
        yb, wbb + (size_t)(2 * i + 1) * 147456, xcur, nullptr, bb_s2 + i * 128,
        bb_t2 + i * 128, nullptr, xnxt);
    _Float16* t = xcur;
    xcur = xnxt;
    xnxt = t;
  }

  depth_proj_softmax_kernel<<<dim3(700), 256, 0, stream>>>(xcur, wdp, dp_b, depth16);
  gridsample_kernel<<<dim3(4096), 256, 0, stream>>>(grids, depth16, outp);
}

// Round 10
// 409.539 us; speedup vs baseline: 1.0922x; 1.0020x over previous
//
#include <hip/hip_runtime.h>
#include <math.h>

typedef _Float16 v8h __attribute__((ext_vector_type(8)));
typedef float v4f __attribute__((ext_vector_type(4)));
typedef float v16f __attribute__((ext_vector_type(16)));

// ---------------------------------------------------------------- prep (repack + mlp + convert, ONE launch)
// R10: convert re-batched. R9 counters: prep still 47-56 us at 10% occ even
// with 18.9KB LDS (8 blk/CU possible) -> LDS-cap theory dead. VGPR_Count=64
// is the tell: float v[64] payload cannot fit the 64-VGPR budget, compiler
// serializes the gathers into ~8-load batches. Fix: 32 channels/thread (v[32]
// fits -> all 32 loads in flight), 1400 convert blocks (2x TLP). Store still
// 64B/thread = exactly one cache line.
// blocks [0,64):    rc repack, 2 co per block (LDS transpose, coalesced)
// blocks [64,256):  bb repack, conv k=(bx-64)/32, co-group g=(bx-64)%32 (4 co)
// blocks [256,263): dp copy (flat, coalesced)
// block  263:       tiny MLP + SE sigmoid
// blocks [264,1664): NCHW f32 -> NHWC f16 convert; bid=(bx-264):
//                   pos-block bid>>3 (256 positions), 32-ch group bid&7.
__global__ void __launch_bounds__(256) prep_kernel(
    const float* __restrict__ rc_w, const float* __restrict__ bb_w1,
    const float* __restrict__ bb_w2, const float* __restrict__ dp_w,
    const float* __restrict__ img, const float* __restrict__ sps,
    const float* __restrict__ fc1_w, const float* __restrict__ fc1_b,
    const float* __restrict__ fc2_w, const float* __restrict__ fc2_b,
    const float* __restrict__ se_rw, const float* __restrict__ se_rb,
    const float* __restrict__ se_ew, const float* __restrict__ se_eb,
    _Float16* __restrict__ wrc, _Float16* __restrict__ wbb,
    _Float16* __restrict__ wdp, _Float16* __restrict__ act16,
    float* __restrict__ sig) {
  const int bx = blockIdx.x;
  const int tid = threadIdx.x;
  __shared__ float lds[4612];  // 18,448 B; padded weight stage / mlp buf

  if (bx < 64) {  // ---- rc repack: co-group of 2, src 2x2304 f32 coalesced
    const float* src = rc_w + (size_t)bx * 2 * 2304;
#pragma unroll
    for (int r = 0; r < 18; ++r) {
      int e = r * 256 + tid;            // 0..4607
      int col = e / 2304;               // 0..1
      int rem = e - col * 2304;
      lds[col * 2305 + rem] = src[e];   // +1 pad breaks col-bank aliasing
    }
    __syncthreads();
#pragma unroll
    for (int ro = 0; ro < 3; ++ro) {
      int lidx = ro * 256 + tid;  // 576 slots = 16 c16 x 9 tap x 2 kh x 2 col
      if (lidx < 576) {
        int col = lidx & 1;
        int r = lidx >> 1;        // ((c16*9+tap)*2+kh)
        int kh = r & 1;
        int ct = r >> 1;
        int tap = ct % 9, c16 = ct / 9;
        v8h o;
#pragma unroll
        for (int j = 0; j < 8; ++j)
          o[j] = (_Float16)lds[col * 2305 + (c16 * 16 + kh * 8 + j) * 9 + tap];
        *(v8h*)(wrc + ((size_t)r * 128 + bx * 2 + col) * 8) = o;
      }
    }
  } else if (bx < 256) {  // ---- bb repack: conv k, co-group of 4
    const int t = bx - 64;
    const int k = t >> 5, g = t & 31;
    const float* base = (k < 3) ? (bb_w1 + (size_t)k * 147456)
                                : (bb_w2 + (size_t)(k - 3) * 147456);
    const int cslot = (k < 3) ? (2 * k) : (2 * (k - 3) + 1);
    const float* src = base + (size_t)g * 4 * 1152;
#pragma unroll
    for (int r = 0; r < 18; ++r) {
      int e = r * 256 + tid;            // 0..4607
      int col = e / 1152;               // 0..3
      int rem = e - col * 1152;
      lds[col * 1153 + rem] = src[e];
    }
    __syncthreads();
#pragma unroll
    for (int ro = 0; ro < 3; ++ro) {
      int lidx = ro * 256 + tid;  // 576 slots = 8 c16 x 9 tap x 2 kh x 4 col
      if (lidx < 576) {
        int col = lidx & 3;
        int r = lidx >> 2;        // ((c16*9+tap)*2+kh), c16<8
        int kh = r & 1;
        int ct = r >> 1;
        int tap = ct % 9, c16 = ct / 9;
        v8h o;
#pragma unroll
        for (int j = 0; j < 8; ++j)
          o[j] = (_Float16)lds[col * 1153 + (c16 * 16 + kh * 8 + j) * 9 + tap];
        *(v8h*)(wbb + (size_t)cslot * 147456 + ((size_t)r * 128 + g * 4 + col) * 8) = o;
      }
    }
  } else if (bx < 263) {  // ---- dp: flat, coalesced both sides
    int s3 = (bx - 256) * 256 + tid;  // < 1792
    v8h o;
#pragma unroll
    for (int j = 0; j < 8; ++j) o[j] = (_Float16)dp_w[(size_t)s3 * 8 + j];
    *(v8h*)(wdp + (size_t)s3 * 8) = o;
  } else if (bx == 263) {  // ---- mlp (first 128 lanes compute; barriers uniform)
    const int j = tid;
    const bool on = j < 128;
    for (int b = 0; b < 4; ++b) {
      float h1 = 0.f;
      if (on) h1 = fmaxf(sps[b] * fc1_w[j] + fc1_b[j], 0.f);
      __syncthreads();
      if (on) lds[j] = h1;
      __syncthreads();
      float hm = 0.f;
      if (on) {
        hm = fc2_b[j];
        for (int k = 0; k < 128; ++k) hm += lds[k] * fc2_w[j * 128 + k];
      }
      __syncthreads();
      if (on) lds[j] = hm;
      __syncthreads();
      float t = 0.f;
      if (on) {
        t = se_rb[j];
        for (int k = 0; k < 128; ++k) t += lds[k] * se_rw[j * 128 + k];
        t = fmaxf(t, 0.f);
      }
      __syncthreads();
      if (on) lds[j] = t;
      __syncthreads();
      if (on) {
        float se = se_eb[j];
        for (int k = 0; k < 128; ++k) se += lds[k] * se_ew[j * 128 + k];
        sig[b * 128 + j] = 1.f / (1.f + expf(-se));
      }
      __syncthreads();
    }
  } else {  // ---- convert: 1400 blocks, no LDS use, 32 loads in flight
    const int bid = bx - 264;                      // 0..1399
    const int cq = bid & 7;                        // 32-ch group 0..7
    const int i = (bid >> 3) * 256 + tid;          // 0..44799
    const int n = i / 11200;
    const int hw = i - n * 11200;
    const float* ip = img + (size_t)n * 2867200 + (size_t)(cq * 32) * 11200 + hw;
    float v[32];
#pragma unroll
    for (int k = 0; k < 32; ++k) v[k] = ip[(size_t)k * 11200];
    _Float16* op = act16 + (size_t)i * 256 + cq * 32;
#pragma unroll
    for (int g = 0; g < 4; ++g) {
      v8h o;
#pragma unroll
      for (int j = 0; j < 8; ++j) o[j] = (_Float16)v[g * 8 + j];
      *(v8h*)(op + g * 8) = o;
    }
  }
}

// ---------------------------------------------------------------- 3x3 conv, implicit GEMM, 32x32x16 f16 MFMA
// R9/R7 conv (best measured: 42.6-43.0 us rc). Conv-structure iteration
// CLOSED: 8 variants all land 43-54 us, MfmaUtil 21-27%, no saturated pipe.
// Tile: 8h x 32w x 64cout, grid 7x7x8 = 392 blocks, 512 thr / 8 waves,
// wave tile 2h x 32w x 32cout. 2-deep named prefetch stages; dx-outer
// dy-reuse compute (4 A-reads serve 6 MFMAs). LDS 58.6 KB -> 2 blocks/CU.
// MODE 0: out = relu((conv + bias)*s + t) * sig_se          (rc conv)
// MODE 1: out = relu(conv*s + t)                            (bb conv1)
// MODE 2: out = relu(xprev + conv*s + t)                    (bb conv2 + residual)
template <int CIN, int MODE>
__global__ void __launch_bounds__(512, 4) conv3x3_kernel(
    const _Float16* __restrict__ act, const _Float16* __restrict__ wr,
    const _Float16* __restrict__ xprev, const float* __restrict__ bias,
    const float* __restrict__ sc, const float* __restrict__ tr,
    const float* __restrict__ sig_se, _Float16* __restrict__ out) {
  constexpr int NCH = CIN / 16;  // 16 (rc) or 8 (bb); always even
  const int wt = blockIdx.x, ht = blockIdx.y;
  const int n = blockIdx.z >> 1, cg = blockIdx.z & 1;
  const int h0 = ht * 8, w0 = wt * 32;
  const int tid = threadIdx.x;
  const int wave = tid >> 6, lane = tid & 63;
  const int l31 = lane & 31, khalf = lane >> 5;
  const int wv = wave >> 1, kc = wave & 1;

  __shared__ alignas(16) _Float16 ldsA[2][2 * 340 * 8];  // 10,880 B per buf
  __shared__ alignas(16) _Float16 ldsB[2][1152 * 8];     // 18,432 B per buf

  // ---- A staging map: 680 v8h slots (2 parts x 340 pos) over 2 rounds
  size_t goffA[2];
  int loffA[2];
  bool exA[2], okA[2];
#pragma unroll
  for (int it = 0; it < 2; ++it) {
    int slot = it * 512 + tid;
    int pos = slot >> 1, part = slot & 1;  // 2 lanes = 32B contiguous global
    int hh = pos / 34, ww = pos - hh * 34;
    int gh = h0 - 1 + hh, gw = w0 - 1 + ww;
    exA[it] = slot < 680;
    bool inimg = (unsigned)gh < 56u && (unsigned)gw < 200u;
    okA[it] = exA[it] && inimg;
    loffA[it] = (part * 340 + pos) * 8;
    int ghc = okA[it] ? gh : 0, gwc = okA[it] ? gw : 0;
    goffA[it] = (((size_t)n * 56 + ghc) * 200 + gwc) * CIN + part * 8;
  }
  // ---- B staging map: 1152 v8h slots (9 tap x 2 kh x 64 cout) over 3 rounds
  size_t goffB[3];
  int loffB[3];
  bool exB[3];
#pragma unroll
  for (int it = 0; it < 3; ++it) {
    int slot = it * 512 + tid;
    exB[it] = slot < 1152;
    int s = exB[it] ? slot : 0;
    int tap = s >> 7, kh = (s >> 6) & 1, co = s & 63;
    goffB[it] = (((size_t)(tap * 2 + kh)) * 128 + cg * 64 + co) * 8;  // chunk-0 offset
    loffB[it] = s * 8;
  }

  const v8h zero8 = {(_Float16)0, (_Float16)0, (_Float16)0, (_Float16)0,
                     (_Float16)0, (_Float16)0, (_Float16)0, (_Float16)0};
  // ---- two named prefetch stages (even chunks -> 0, odd chunks -> 1)
  v8h preA0[2], preB0[3], preA1[2], preB1[3];
#pragma unroll
  for (int it = 0; it < 2; ++it) {
    preA0[it] = okA[it] ? *(const v8h*)(act + goffA[it]) : zero8;
    preA1[it] = okA[it] ? *(const v8h*)(act + goffA[it] + 16) : zero8;
  }
#pragma unroll
  for (int it = 0; it < 3; ++it) {
    preB0[it] = exB[it] ? *(const v8h*)(wr + goffB[it]) : zero8;
    preB1[it] = exB[it] ? *(const v8h*)(wr + goffB[it] + 18432) : zero8;
  }

  v16f acc[2];
#pragma unroll
  for (int mt = 0; mt < 2; ++mt)
#pragma unroll
    for (int r = 0; r < 16; ++r) acc[mt][r] = 0.f;

  // per-chunk compute: dx outer, 4 A-rows reused across dy (6 MFMAs / 4 reads)
  auto compute = [&](const _Float16* aB, const _Float16* bB) {
#pragma unroll
    for (int dx = 0; dx < 3; ++dx) {
      v8h a[4];
#pragma unroll
      for (int r = 0; r < 4; ++r)
        a[r] = *(const v8h*)(aB + (khalf * 340 + (wv * 2 + r) * 34 + l31 + dx) * 8);
#pragma unroll
      for (int dy = 0; dy < 3; ++dy) {
        v8h bf = *(const v8h*)(bB + ((dy * 3 + dx) * 128 + khalf * 64 + kc * 32 + l31) * 8);
        acc[0] = __builtin_amdgcn_mfma_f32_32x32x16_f16(a[dy], bf, acc[0], 0, 0, 0);
        acc[1] = __builtin_amdgcn_mfma_f32_32x32x16_f16(a[dy + 1], bf, acc[1], 0, 0, 0);
      }
    }
  };

#pragma unroll 1
  for (int c = 0; c < NCH; c += 2) {
    // ---- even chunk c: commit stage 0, refill for c+2, compute buf 0
#pragma unroll
    for (int it = 0; it < 2; ++it)
      if (exA[it]) *(v8h*)(&ldsA[0][0] + loffA[it]) = preA0[it];
#pragma unroll
    for (int it = 0; it < 3; ++it)
      if (exB[it]) *(v8h*)(&ldsB[0][0] + loffB[it]) = preB0[it];
    if (c + 2 < NCH) {
#pragma unroll
      for (int it = 0; it < 2; ++it)
        preA0[it] = okA[it] ? *(const v8h*)(act + goffA[it] + (size_t)(c + 2) * 16) : zero8;
#pragma unroll
      for (int it = 0; it < 3; ++it)
        preB0[it] = exB[it] ? *(const v8h*)(wr + goffB[it] + (size_t)(c + 2) * 18432) : zero8;
    }
    __syncthreads();
    compute(&ldsA[0][0], &ldsB[0][0]);

    // ---- odd chunk c+1: commit stage 1, refill for c+3, compute buf 1
#pragma unroll
    for (int it = 0; it < 2; ++it)
      if (exA[it]) *(v8h*)(&ldsA[1][0] + loffA[it]) = preA1[it];
#pragma unroll
    for (int it = 0; it < 3; ++it)
      if (exB[it]) *(v8h*)(&ldsB[1][0] + loffB[it]) = preB1[it];
    if (c + 3 < NCH) {
#pragma unroll
      for (int it = 0; it < 2; ++it)
        preA1[it] = okA[it] ? *(const v8h*)(act + goffA[it] + (size_t)(c + 3) * 16) : zero8;
#pragma unroll
      for (int it = 0; it < 3; ++it)
        preB1[it] = exB[it] ? *(const v8h*)(wr + goffB[it] + (size_t)(c + 3) * 18432) : zero8;
    }
    __syncthreads();
    compute(&ldsA[1][0], &ldsB[1][0]);
  }

  // epilogue: D layout col(N=cout)=l31, row(M=w-offset)=(r&3)+8*(r>>2)+4*khalf
#pragma unroll
  for (int mt = 0; mt < 2; ++mt) {
    const int h = h0 + wv * 2 + mt;
    const int cc = cg * 64 + kc * 32 + l31;
    const float s = sc[cc], t = tr[cc];
    float bb = 0.f, sg = 1.f;
    if constexpr (MODE == 0) {
      bb = bias[cc];
      sg = sig_se[n * 128 + cc];
    }
#pragma unroll
    for (int r = 0; r < 16; ++r) {
      const int m = (r & 3) + 8 * (r >> 2) + 4 * khalf;
      const int w = w0 + m;
      if (w < 200) {
        float v = acc[mt][r];
        size_t oidx = (((size_t)n * 56 + h) * 200 + w) * 128 + cc;
        if constexpr (MODE == 0) v = fmaxf((v + bb) * s + t, 0.f) * sg;
        if constexpr (MODE == 1) v = fmaxf(v * s + t, 0.f);
        if constexpr (MODE == 2) v = fmaxf((float)xprev[oidx] + v * s + t, 0.f);
        out[oidx] = (_Float16)v;
      }
    }
  }
}

// ---------------------------------------------------------------- depth proj (MFMA) + fused softmax
// x: [44800][128] f16; wdp: [112][128] f16; dp_b: [112] f32
// depth out: f16 [pos][112] (z-contiguous for gridsample)
__global__ void __launch_bounds__(256) depth_proj_softmax_kernel(
    const _Float16* __restrict__ x, const _Float16* __restrict__ wdp,
    const float* __restrict__ dp_b, _Float16* __restrict__ depth) {
  const int wave = threadIdx.x >> 6, lane = threadIdx.x & 63;
  const int q = lane >> 4, l16 = lane & 15;
  const int pos0 = blockIdx.x * 64 + wave * 16;

  v4f acc[7];
#pragma unroll
  for (int nt = 0; nt < 7; ++nt) {
    float bv = dp_b[nt * 16 + l16];
    acc[nt] = {bv, bv, bv, bv};
  }
#pragma unroll
  for (int c0 = 0; c0 < 128; c0 += 32) {
    v8h a = *(const v8h*)(x + (size_t)(pos0 + l16) * 128 + c0 + q * 8);
#pragma unroll
    for (int nt = 0; nt < 7; ++nt) {
      v8h b = *(const v8h*)(wdp + (size_t)(nt * 16 + l16) * 128 + c0 + q * 8);
      acc[nt] = __builtin_amdgcn_mfma_f32_16x16x32_f16(a, b, acc[nt], 0, 0, 0);
    }
  }
  float m[4];
#pragma unroll
  for (int r = 0; r < 4; ++r) {
    m[r] = acc[0][r];
#pragma unroll
    for (int nt = 1; nt < 7; ++nt) m[r] = fmaxf(m[r], acc[nt][r]);
  }
#pragma unroll
  for (int off = 1; off < 16; off <<= 1)
#pragma unroll
    for (int r = 0; r < 4; ++r) m[r] = fmaxf(m[r], __shfl_xor(m[r], off));
  float s[4] = {0.f, 0.f, 0.f, 0.f};
#pragma unroll
  for (int nt = 0; nt < 7; ++nt)
#pragma unroll
    for (int r = 0; r < 4; ++r) {
      float e = expf(acc[nt][r] - m[r]);
      acc[nt][r] = e;
      s[r] += e;
    }
#pragma unroll
  for (int off = 1; off < 16; off <<= 1)
#pragma unroll
    for (int r = 0; r < 4; ++r) s[r] += __shfl_xor(s[r], off);
#pragma unroll
  for (int r = 0; r < 4; ++r) {
    const float inv = 1.f / s[r];
    const size_t p = pos0 + q * 4 + r;
#pragma unroll
    for (int nt = 0; nt < 7; ++nt)
      depth[p * 112 + nt * 16 + l16] = (_Float16)(acc[nt][r] * inv);
  }
}

// ---------------------------------------------------------------- trilinear grid sample (C=1)
// R10: XCD-pinned by volume. Random grid coords -> zero inter-lane locality;
// each n's depth volume is 2.5 MB (fits one XCD's 4 MiB L2, ~200x line reuse)
// but default round-robin dispatch spreads every n across all 8 XCDs (10 MB
// working set thrashes). Bijective swizzle: XCD x serves n = x>>1 only.
__global__ void __launch_bounds__(256) gridsample_kernel(
    const float* __restrict__ grids, const _Float16* __restrict__ depth,
    float* __restrict__ out) {
  const int b = blockIdx.x;
  const int x = b & 7, s = b >> 3;                 // XCD id (dispatch %8), slot
  const int i0 = (x >> 1) * 1024 + (x & 1) * 512 + s;  // bijective on [0,4096)
  const int i = i0 * 256 + (int)threadIdx.x;
  const int n = i >> 18;
  const float gx = grids[(size_t)i * 3];
  const float gy = grids[(size_t)i * 3 + 1];
  const float gz = grids[(size_t)i * 3 + 2];
  const float ix = (gx + 1.f) * 100.f - 0.5f;
  const float iy = (gy + 1.f) * 28.f - 0.5f;
  const float iz = (gz + 1.f) * 56.f - 0.5f;
  const float xf = floorf(ix), yf = floorf(iy), zf = floorf(iz);
  const int x0 = (int)xf, y0 = (int)yf, z0 = (int)zf;
  const float fx = ix - xf, fy = iy - yf, fz = iz - zf;
  const bool zv0 = (unsigned)z0 < 112u;
  const bool zv1 = (unsigned)(z0 + 1) < 112u;
  const float wz0 = 1.f - fz, wz1 = fz;
  float acc = 0.f;
#pragma unroll
  for (int dy = 0; dy < 2; ++dy) {
    const int yi = y0 + dy;
    const float wy = dy ? fy : 1.f - fy;
#pragma unroll
    for (int dx = 0; dx < 2; ++dx) {
      const int xi = x0 + dx;
      const float wx = dx ? fx : 1.f - fx;
      if ((unsigned)xi < 200u && (unsigned)yi < 56u) {
        const _Float16* bp = depth + ((size_t)n * 11200 + yi * 200 + xi) * 112;
        float v0 = zv0 ? (float)bp[z0] : 0.f;
        float v1 = zv1 ? (float)bp[z0 + 1] : 0.f;
        acc += (wx * wy) * (wz0 * v0 + wz1 * v1);
      }
    }
  }
  out[i] = acc;
}

// ---------------------------------------------------------------- launch
extern "C" void kernel_launch(void* const* d_in, const int* in_sizes, int n_in,
                              void* d_out, int out_size, void* d_ws, size_t ws_size,
                              hipStream_t stream) {
  (void)in_sizes; (void)n_in; (void)out_size; (void)ws_size;
  const float* img = (const float*)d_in[0];
  const float* sps = (const float*)d_in[1];
  const float* grids = (const float*)d_in[2];
  const float* rc_w = (const float*)d_in[3];
  const float* rc_b = (const float*)d_in[4];
  const float* rc_s = (const float*)d_in[5];
  const float* rc_t = (const float*)d_in[6];
  const float* fc1_w = (const float*)d_in[7];
  const float* fc1_b = (const float*)d_in[8];
  const float* fc2_w = (const float*)d_in[9];
  const float* fc2_b = (const float*)d_in[10];
  const float* se_rw = (const float*)d_in[11];
  const float* se_rb = (const float*)d_in[12];
  const float* se_ew = (const float*)d_in[13];
  const float* se_eb = (const float*)d_in[14];
  const float* bb_w1 = (const float*)d_in[15];
  const float* bb_s1 = (const float*)d_in[16];
  const float* bb_t1 = (const float*)d_in[17];
  const float* bb_w2 = (const float*)d_in[18];
  const float* bb_s2 = (const float*)d_in[19];
  const float* bb_t2 = (const float*)d_in[20];
  const float* dp_w = (const float*)d_in[21];
  const float* dp_b = (const float*)d_in[22];
  float* outp = (float*)d_out;

  char* ws = (char*)d_ws;
  _Float16* act16 = (_Float16*)(ws + 0);
  _Float16* depth16 = (_Float16*)(ws + 0);  // reuses act16 slot (act16 dead post rc-conv)
  _Float16* xa = (_Float16*)(ws + 23068672);
  _Float16* xb = (_Float16*)(ws + 23068672 + 11534336);
  _Float16* yb = (_Float16*)(ws + 23068672 + 2 * 11534336);
  _Float16* wrc = (_Float16*)(ws + 57671680);           // 589,824 B
  _Float16* wdp = (_Float16*)(ws + 57671680 + 589824);  // 28,672 B
  _Float16* wbb = (_Float16*)(ws + 58327040);           // 1,769,472 B
  float* sig = (float*)(ws + 58327040 + 1769472);       // 2,048 B

  prep_kernel<<<dim3(1664), 256, 0, stream>>>(
      rc_w, bb_w1, bb_w2, dp_w, img, sps, fc1_w, fc1_b, fc2_w, fc2_b, se_rw, se_rb,
      se_ew, se_eb, wrc, wbb, wdp, act16, sig);

  dim3 cgrid(7, 7, 8);  // 8h x 32w x 64cout, z = n*2 + cg, 392 blocks x 8 waves
  conv3x3_kernel<256, 0><<<cgrid, 512, 0, stream>>>(act16, wrc, nullptr, rc_b, rc_s,
                                                    rc_t, sig, xa);
  _Float16* xcur = xa;
  _Float16* xnxt = xb;
  for (int i = 0; i < 3; ++i) {
    conv3x3_kernel<128, 1><<<cgrid, 512, 0, stream>>>(
        xcur, wbb + (size_t)(2 * i) * 147456, nullptr, nullptr, bb_s1 + i * 128,
        bb_t1 + i * 128, nullptr, yb);
    conv3x3_kernel<128, 2><<<cgrid, 512, 0, stream>>>(
        yb, wbb + (size_t)(2 * i + 1) * 147456, xcur, nullptr, bb_s2 + i * 128,
        bb_t2 + i * 128, nullptr, xnxt);
    _Float16* t = xcur;
    xcur = xnxt;
    xnxt = t;
  }

  depth_proj_softmax_kernel<<<dim3(700), 256, 0, stream>>>(xcur, wdp, dp_b, depth16);
  gridsample_kernel<<<dim3(4096), 256, 0, stream>>>(grids, depth16, outp);
}